// Round 3
// baseline (439.080 us; speedup 1.0000x reference)
//
#include <hip/hip_runtime.h>
#include <math.h>

// Problem constants (B=2, S=2048 -> N=4096 tokens)
#define NTOK 4096
#define DDIM 512
#define HDIM 2048
#define NEXP 16
#define NSLOT 8192

// Workspace layout (bytes). Total ~117.4 MB (proven <= R2's 125.8 MB usage).
#define WS_COUNTS    0u
#define WS_OFFSETS   256u
#define WS_NTILES    512u        // [0]=nt128 (gemm2), [1]=nt256 (gemm1)
#define WS_TILEMAP1  768u        // 128-tiles, <=80 ints
#define WS_TILEMAP2  1280u       // 256-tiles, <=48 ints
#define WS_TOKLIST   36864u      // NEXP*NTOK ints (256 KB)
#define WS_WLIST     299008u     // NEXP*NTOK floats
#define WS_XB        1048576u    // NTOK*DDIM bf16 (4 MB)
#define WS_W1T       8388608u    // [E][H][D] bf16 (33.5 MB)
#define WS_W2T       41943040u   // [E][D][H] bf16 (33.5 MB)
#define WS_HBUF      75497472u   // [NSLOT][H] bf16 (33.5 MB)
#define WS_YACC      109051904u  // [NTOK][D] f32 (8.4 MB), atomically accumulated

typedef __attribute__((ext_vector_type(8))) short short8;
typedef __attribute__((ext_vector_type(4))) float floatx4;
typedef unsigned short ushort_t;

__device__ __forceinline__ ushort_t f2bf(float f) {
    unsigned u = __float_as_uint(f);
    u += 0x7fffu + ((u >> 16) & 1u);   // round-to-nearest-even
    return (ushort_t)(u >> 16);
}

__device__ __forceinline__ void gload_lds16(const void* g, void* l) {
    __builtin_amdgcn_global_load_lds(
        (const __attribute__((address_space(1))) unsigned int*)g,
        (__attribute__((address_space(3))) unsigned int*)l, 16, 0, 0);
}

// ---------------- gating: 8 tokens/block, x+Wg staged in LDS ---------------
// Thread = (token tl 0..7, expert e 0..15, half h 0..1). fp32 logits (top-2
// selection must match fp32 reference). Also emits xb (bf16 copy of x).
__global__ __launch_bounds__(256) void gating_kernel(
    const float* __restrict__ x, const float* __restrict__ Wg,
    const float* __restrict__ bg, int* __restrict__ counts,
    int* __restrict__ tok_list, float* __restrict__ w_list,
    ushort_t* __restrict__ xb)
{
    __shared__ float xs[8][520];       // pad 512->520: bank-spread tl groups
    __shared__ float wgs[512 * 16];    // natural [d][e] layout
    __shared__ float ls[8][16][2];

    const int tid = threadIdx.x;
    const int t0 = blockIdx.x * 8;
    const float* xg = x + (size_t)t0 * DDIM;
    ushort_t* xbg = xb + (size_t)t0 * DDIM;

    #pragma unroll
    for (int p = 0; p < 4; ++p) {
        const int idx = p * 1024 + tid * 4;
        const float4 v = *(const float4*)(xg + idx);
        *(float4*)&xs[idx >> 9][idx & 511] = v;
        *(ushort4*)(xbg + idx) =
            make_ushort4(f2bf(v.x), f2bf(v.y), f2bf(v.z), f2bf(v.w));
    }
    #pragma unroll
    for (int p = 0; p < 8; ++p) {
        const int i = p * 1024 + tid * 4;
        *(float4*)&wgs[i] = *(const float4*)(Wg + i);
    }
    __syncthreads();

    const int tl = tid >> 5;
    const int e  = (tid >> 1) & 15;
    const int h  = tid & 1;
    float a0 = 0.f, a1 = 0.f, a2 = 0.f, a3 = 0.f;
    #pragma unroll 8
    for (int it = 0; it < 64; ++it) {
        const int d = h * 256 + it * 4;
        const float4 xv = *(const float4*)&xs[tl][d];
        a0 = fmaf(xv.x, wgs[(d + 0) * 16 + e], a0);
        a1 = fmaf(xv.y, wgs[(d + 1) * 16 + e], a1);
        a2 = fmaf(xv.z, wgs[(d + 2) * 16 + e], a2);
        a3 = fmaf(xv.w, wgs[(d + 3) * 16 + e], a3);
    }
    ls[tl][e][h] = (a0 + a1) + (a2 + a3);
    __syncthreads();

    if ((tid & 31) == 0) {   // one thread per token: tid = tl*32
        float l[16];
        #pragma unroll
        for (int j = 0; j < NEXP; ++j) l[j] = ls[tl][j][0] + ls[tl][j][1] + bg[j];
        float m = -1e30f;
        #pragma unroll
        for (int j = 0; j < NEXP; ++j) m = fmaxf(m, l[j]);
        float s = 0.f;
        #pragma unroll
        for (int j = 0; j < NEXP; ++j) s += __expf(l[j] - m);
        int i0 = 0; float v0 = -1e30f;
        #pragma unroll
        for (int j = 0; j < NEXP; ++j)
            if (l[j] > v0) { v0 = l[j]; i0 = j; }
        int i1 = -1; float v1 = -1e30f;
        #pragma unroll
        for (int j = 0; j < NEXP; ++j)
            if (j != i0 && l[j] > v1) { v1 = l[j]; i1 = j; }
        const float w0 = __expf(v0 - m) / s;
        const float w1 = __expf(v1 - m) / s;
        const int t = t0 + tl;
        int p0 = atomicAdd(&counts[i0], 1);
        tok_list[i0 * NTOK + p0] = t;
        w_list[i0 * NTOK + p0] = w0;
        int p1 = atomicAdd(&counts[i1], 1);
        tok_list[i1 * NTOK + p1] = t;
        w_list[i1 * NTOK + p1] = w1;
    }
}

// offsets prefix-scan + tile lists (128-tiles for gemm2, 256-tiles for gemm1)
__global__ void scan_kernel(const int* __restrict__ counts, int* __restrict__ offsets,
                            int* __restrict__ tm128, int* __restrict__ tm256,
                            int* __restrict__ ntiles)
{
    if (threadIdx.x == 0 && blockIdx.x == 0) {
        int s = 0, n1 = 0, n2 = 0;
        for (int e = 0; e < NEXP; ++e) {
            offsets[e] = s;
            const int c = counts[e];
            s += c;
            const int t1 = (c + 127) >> 7;
            for (int i = 0; i < t1; ++i) tm128[n1++] = (e << 16) | i;
            const int t2 = (c + 255) >> 8;
            for (int i = 0; i < t2; ++i) tm256[n2++] = (e << 16) | i;
        }
        offsets[NEXP] = s;
        ntiles[0] = n1;
        ntiles[1] = n2;
    }
}

// Fused W1+W2 transpose+convert: [z][R][C] fp32 -> [z][C][R] bf16, 64x64 tiles.
__global__ __launch_bounds__(256) void transpose2_kernel(
    const float* __restrict__ W1, const float* __restrict__ W2,
    ushort_t* __restrict__ W1t, ushort_t* __restrict__ W2t)
{
    __shared__ float tile[64][65];
    int bid = blockIdx.x;
    const float* src; ushort_t* dst; int R, C, rt, ct, e;
    if (bid < 4096) {              // W1: R=512, C=2048, 8x32 tiles/expert
        e = bid >> 8; const int rem = bid & 255;
        rt = rem >> 5; ct = rem & 31;
        src = W1; dst = W1t; R = DDIM; C = HDIM;
    } else {                       // W2: R=2048, C=512, 32x8 tiles/expert
        bid -= 4096;
        e = bid >> 8; const int rem = bid & 255;
        rt = rem >> 3; ct = rem & 7;
        src = W2; dst = W2t; R = HDIM; C = DDIM;
    }
    const size_t zoff = (size_t)e * R * C;
    const int r0 = rt << 6, c0 = ct << 6;
    const int tid = threadIdx.x;
    const int rr4 = (tid & 15) << 2;
    const int qq  = tid >> 4;
    #pragma unroll
    for (int p = 0; p < 4; ++p) {
        const int r = qq + (p << 4);
        const float4 v = *(const float4*)(src + zoff + (size_t)(r0 + r) * C + c0 + rr4);
        tile[r][rr4 + 0] = v.x; tile[r][rr4 + 1] = v.y;
        tile[r][rr4 + 2] = v.z; tile[r][rr4 + 3] = v.w;
    }
    __syncthreads();
    #pragma unroll
    for (int p = 0; p < 4; ++p) {
        const int c = qq + (p << 4);
        ushort4 o = make_ushort4(f2bf(tile[rr4 + 0][c]), f2bf(tile[rr4 + 1][c]),
                                 f2bf(tile[rr4 + 2][c]), f2bf(tile[rr4 + 3][c]));
        *(ushort4*)(dst + zoff + (size_t)(c0 + c) * R + r0 + rr4) = o;
    }
}

// ---------------- GEMM1: 256x128 tile, BK=32, LDS layout [chunk][row][8] ----
// Wave w owns rows w*64..+63, all 128 n. 32 MFMA / 12 ds_read_b128 per iter.
// Frag reads hit exactly 8 words/bank (b128 floor, conflict-free).
__global__ __launch_bounds__(256) void gemm1_mfma(
    const ushort_t* __restrict__ xb, const ushort_t* __restrict__ W1t,
    const float* __restrict__ b1, const int* __restrict__ tok_list,
    const int* __restrict__ counts, const int* __restrict__ offsets,
    const int* __restrict__ tm256, const int* __restrict__ ntiles,
    ushort_t* __restrict__ hbuf)
{
    if ((int)blockIdx.y >= ntiles[1]) return;
    const int tm = tm256[blockIdx.y];
    const int e  = tm >> 16;
    const int m0 = (tm & 0xffff) << 8;
    const int Me = counts[e];
    const int aoff = offsets[e];
    const int n0 = blockIdx.x << 7;

    __shared__ __align__(16) ushort_t As[4 * 256 * 8];   // 16 KB
    __shared__ __align__(16) ushort_t Bs[4 * 128 * 8];   // 8 KB

    const int tid = threadIdx.x;
    const int lane = tid & 63;
    const int w = tid >> 6;

    const int rowA = (w << 6) + lane;
    const int tokA = tok_list[e * NTOK + min(m0 + rowA, Me - 1)];
    const ushort_t* gA = xb + (size_t)tokA * DDIM;

    const int rowB = ((w & 1) << 6) + lane;
    const int c2 = (w >> 1) << 1;
    const ushort_t* gB = W1t + ((size_t)e * HDIM + n0 + rowB) * DDIM + c2 * 8;

    ushort_t* lA = As + ((w << 6) << 3);               // rows w*64.., chunk c added per issue
    ushort_t* lB = Bs + ((c2 << 7) + ((w & 1) << 6) << 3);

    const int fm = lane & 15, fq = lane >> 4;
    floatx4 acc[4][8] = {};

    for (int k0 = 0; k0 < DDIM; k0 += 32) {
        gload_lds16(gA + k0 +  0, lA);
        gload_lds16(gA + k0 +  8, lA + 256 * 8);
        gload_lds16(gA + k0 + 16, lA + 512 * 8);
        gload_lds16(gA + k0 + 24, lA + 768 * 8);
        gload_lds16(gB + k0 + 0, lB);
        gload_lds16(gB + k0 + 8, lB + 128 * 8);
        __syncthreads();
        short8 af[4], bf[8];
        #pragma unroll
        for (int i = 0; i < 4; ++i)
            af[i] = *(const short8*)(As + (((fq << 8) + (w << 6) + (i << 4) + fm) << 3));
        #pragma unroll
        for (int j = 0; j < 8; ++j)
            bf[j] = *(const short8*)(Bs + (((fq << 7) + (j << 4) + fm) << 3));
        #pragma unroll
        for (int i = 0; i < 4; ++i)
            #pragma unroll
            for (int j = 0; j < 8; ++j)
                acc[i][j] = __builtin_amdgcn_mfma_f32_16x16x32_bf16(
                    af[i], bf[j], acc[i][j], 0, 0, 0);
        __syncthreads();
    }

    #pragma unroll
    for (int j = 0; j < 8; ++j) {
        const int n = n0 + (j << 4) + fm;
        const float bias = b1[e * HDIM + n];
        #pragma unroll
        for (int i = 0; i < 4; ++i) {
            #pragma unroll
            for (int r = 0; r < 4; ++r) {
                const int m = m0 + (w << 6) + (i << 4) + (fq << 2) + r;
                if (m < Me) {
                    const float v = fmaxf(acc[i][j][r] + bias, 0.f);
                    hbuf[(size_t)(aoff + m) * HDIM + n] = f2bf(v);
                }
            }
        }
    }
}

// ---------------- GEMM2: 128x128 tile, BK=32, split-K=2, atomic per-token ---
__global__ __launch_bounds__(256) void gemm2_mfma(
    const ushort_t* __restrict__ hbuf, const ushort_t* __restrict__ W2t,
    const float* __restrict__ b2, const float* __restrict__ w_list,
    const int* __restrict__ tok_list, const int* __restrict__ counts,
    const int* __restrict__ offsets, const int* __restrict__ tm128,
    const int* __restrict__ ntiles, float* __restrict__ yacc)
{
    if ((int)blockIdx.y >= ntiles[0]) return;
    const int tm = tm128[blockIdx.y];
    const int e  = tm >> 16;
    const int m0 = (tm & 0xffff) << 7;
    const int Me = counts[e];
    const int aoff = offsets[e];
    const int n0 = blockIdx.x << 7;
    const int kb = blockIdx.z << 10;    // k-half base: 0 or 1024

    __shared__ __align__(16) ushort_t As[4 * 128 * 8];   // 8 KB
    __shared__ __align__(16) ushort_t Bs[4 * 128 * 8];   // 8 KB

    const int tid = threadIdx.x;
    const int lane = tid & 63;
    const int w = tid >> 6;

    const int rA0 = aoff + min(m0 + lane, Me - 1);
    const int rA1 = aoff + min(m0 + 64 + lane, Me - 1);
    const ushort_t* gA0 = hbuf + (size_t)rA0 * HDIM + kb + w * 8;   // chunk w
    const ushort_t* gA1 = hbuf + (size_t)rA1 * HDIM + kb + w * 8;
    const ushort_t* gB0 = W2t + ((size_t)e * DDIM + n0 + lane) * HDIM + kb + w * 8;
    const ushort_t* gB1 = gB0 + (size_t)64 * HDIM;

    ushort_t* lA = As + ((w << 7) << 3);
    ushort_t* lB = Bs + ((w << 7) << 3);

    const int fm = lane & 15, fq = lane >> 4;
    const int wr = (w >> 1) << 6, wc = (w & 1) << 6;
    floatx4 acc[4][4] = {};

    for (int k0 = 0; k0 < 1024; k0 += 32) {
        gload_lds16(gA0 + k0, lA);
        gload_lds16(gA1 + k0, lA + 64 * 8);
        gload_lds16(gB0 + k0, lB);
        gload_lds16(gB1 + k0, lB + 64 * 8);
        __syncthreads();
        short8 af[4], bf[4];
        #pragma unroll
        for (int i = 0; i < 4; ++i)
            af[i] = *(const short8*)(As + (((fq << 7) + wr + (i << 4) + fm) << 3));
        #pragma unroll
        for (int j = 0; j < 4; ++j)
            bf[j] = *(const short8*)(Bs + (((fq << 7) + wc + (j << 4) + fm) << 3));
        #pragma unroll
        for (int i = 0; i < 4; ++i)
            #pragma unroll
            for (int j = 0; j < 4; ++j)
                acc[i][j] = __builtin_amdgcn_mfma_f32_16x16x32_bf16(
                    af[i], bf[j], acc[i][j], 0, 0, 0);
        __syncthreads();
    }

    const bool first = (blockIdx.z == 0);
    #pragma unroll
    for (int i = 0; i < 4; ++i) {
        #pragma unroll
        for (int r = 0; r < 4; ++r) {
            const int m = m0 + wr + (i << 4) + (fq << 2) + r;
            if (m < Me) {
                const int tok = tok_list[e * NTOK + m];
                const float gw = w_list[e * NTOK + m];
                float* yrow = yacc + (size_t)tok * DDIM;
                #pragma unroll
                for (int j = 0; j < 4; ++j) {
                    const int n = n0 + wc + (j << 4) + fm;
                    const float bias = first ? b2[e * DDIM + n] : 0.f;
                    atomicAdd(yrow + n, gw * (acc[i][j][r] + bias));
                }
            }
        }
    }
}

// out = LayerNorm(x + yacc) * gamma + beta; one wave per token.
__global__ __launch_bounds__(256) void ln_kernel(
    const float* __restrict__ x, const float* __restrict__ yacc,
    const float* __restrict__ gamma, const float* __restrict__ beta,
    float* __restrict__ out)
{
    const int t = blockIdx.x * 4 + (threadIdx.x >> 6);
    const int lane = threadIdx.x & 63;

    float v[8];
    float s = 0.f;
    #pragma unroll
    for (int i = 0; i < 8; ++i) {
        const int d = lane + 64 * i;
        v[i] = x[(size_t)t * DDIM + d] + yacc[(size_t)t * DDIM + d];
        s += v[i];
    }
    #pragma unroll
    for (int o = 32; o > 0; o >>= 1) s += __shfl_xor(s, o, 64);
    const float mu = s * (1.f / DDIM);
    float q = 0.f;
    #pragma unroll
    for (int i = 0; i < 8; ++i) { const float d_ = v[i] - mu; q = fmaf(d_, d_, q); }
    #pragma unroll
    for (int o = 32; o > 0; o >>= 1) q += __shfl_xor(q, o, 64);
    const float rstd = rsqrtf(q * (1.f / DDIM) + 1e-5f);
    #pragma unroll
    for (int i = 0; i < 8; ++i) {
        const int d = lane + 64 * i;
        out[(size_t)t * DDIM + d] = (v[i] - mu) * rstd * gamma[d] + beta[d];
    }
}

extern "C" void kernel_launch(void* const* d_in, const int* in_sizes, int n_in,
                              void* d_out, int out_size, void* d_ws, size_t ws_size,
                              hipStream_t stream) {
    const float* x     = (const float*)d_in[0];
    const float* Wg    = (const float*)d_in[1];
    const float* bg    = (const float*)d_in[2];
    const float* W1    = (const float*)d_in[3];
    const float* b1    = (const float*)d_in[4];
    const float* W2    = (const float*)d_in[5];
    const float* b2    = (const float*)d_in[6];
    const float* gamma = (const float*)d_in[7];
    const float* beta  = (const float*)d_in[8];
    float* out = (float*)d_out;

    char* ws = (char*)d_ws;
    int*      counts   = (int*)(ws + WS_COUNTS);
    int*      offsets  = (int*)(ws + WS_OFFSETS);
    int*      ntiles   = (int*)(ws + WS_NTILES);
    int*      tm128    = (int*)(ws + WS_TILEMAP1);
    int*      tm256    = (int*)(ws + WS_TILEMAP2);
    int*      tok_list = (int*)(ws + WS_TOKLIST);
    float*    w_list   = (float*)(ws + WS_WLIST);
    ushort_t* xb       = (ushort_t*)(ws + WS_XB);
    ushort_t* W1t      = (ushort_t*)(ws + WS_W1T);
    ushort_t* W2t      = (ushort_t*)(ws + WS_W2T);
    ushort_t* hbuf     = (ushort_t*)(ws + WS_HBUF);
    float*    yacc     = (float*)(ws + WS_YACC);

    hipMemsetAsync(counts, 0, 64, stream);
    hipMemsetAsync(yacc, 0, (size_t)NTOK * DDIM * sizeof(float), stream);
    gating_kernel<<<NTOK / 8, 256, 0, stream>>>(x, Wg, bg, counts, tok_list, w_list, xb);
    scan_kernel<<<1, 64, 0, stream>>>(counts, offsets, tm128, tm256, ntiles);
    transpose2_kernel<<<8192, 256, 0, stream>>>(W1, W2, W1t, W2t);
    gemm1_mfma<<<dim3(HDIM / 128, 48), 256, 0, stream>>>(
        xb, W1t, b1, tok_list, counts, offsets, tm256, ntiles, hbuf);
    gemm2_mfma<<<dim3(DDIM / 128, 80, 2), 256, 0, stream>>>(
        hbuf, W2t, b2, w_list, tok_list, counts, offsets, tm128, ntiles, yacc);
    ln_kernel<<<NTOK / 4, 256, 0, stream>>>(x, yacc, gamma, beta, out);
}

// Round 4
// 337.957 us; speedup vs baseline: 1.2992x; 1.2992x over previous
//
#include <hip/hip_runtime.h>
#include <math.h>

// Problem constants (B=2, S=2048 -> N=4096 tokens)
#define NTOK 4096
#define DDIM 512
#define HDIM 2048
#define NEXP 16

// Fragment-tiled layouts: elem(e_or_t, row, k) =
//   ((tile16 * CK + (k>>3)) * 128) + (row&15)*8 + (k&7)
// so a 64-lane b128 load (lane*16B) fetches rows r0..r0+15 x k-chunk32 — one
// MFMA fragment set, fully coalesced. No LDS needed in the GEMM K-loop.

// Workspace layout (bytes). Total ~115 MB (<= known-good 125.8 MB).
#define WS_COUNTS    0u
#define WS_OFFSETS   256u
#define WS_NTILES    512u
#define WS_TM        768u          // <=80 ints
#define WS_EPOS      4096u         // NTOK*2 ints (32 KB)
#define WS_TOK       36864u        // NEXP*NTOK ints (256 KB)
#define WS_WL        299008u       // NEXP*NTOK floats (256 KB)
#define WS_XA        1048576u      // tiled A for gemm1: 80*128*512 bf16 = 10.5 MB
#define WS_W1T       11534336u     // tiled [e][nt128][c64][16][8] bf16 = 33.5 MB
#define WS_W2T       45088768u     // tiled [e][nt32][c256][16][8] bf16 = 33.5 MB
#define WS_HB        78643200u     // tiled [t80][sub8][c256][16][8] bf16 = 41.9 MB
#define WS_YB        WS_W1T        // ybuf [2][8192][512] bf16 = 16.8 MB, aliases W1T
                                   // (W1T dead after gemm1; stream is serial)

typedef __attribute__((ext_vector_type(8))) short short8;
typedef __attribute__((ext_vector_type(4))) float floatx4;
typedef unsigned short ushort_t;

__device__ __forceinline__ ushort_t f2bf(float f) {
    unsigned u = __float_as_uint(f);
    u += 0x7fffu + ((u >> 16) & 1u);   // round-to-nearest-even
    return (ushort_t)(u >> 16);
}
__device__ __forceinline__ float bf2f(ushort_t u) {
    return __uint_as_float((unsigned)u << 16);
}

// ---- prep: blocks 0..511 = gating (8 tokens each); 512..8703 = W transpose --
__global__ __launch_bounds__(256) void prep_kernel(
    const float* __restrict__ x, const float* __restrict__ Wg,
    const float* __restrict__ bg, const float* __restrict__ W1,
    const float* __restrict__ W2, int* __restrict__ counts,
    int* __restrict__ tok_list, float* __restrict__ w_list,
    int* __restrict__ epos, ushort_t* __restrict__ W1t,
    ushort_t* __restrict__ W2t)
{
    __shared__ float smem[4416];
    const int tid = threadIdx.x;
    int bid = blockIdx.x;

    if (bid < 512) {
        // ---------------- gating ----------------
        float (*xs)[520] = (float(*)[520])smem;              // 8x520
        float (*lsm)[16][2] = (float(*)[16][2])(smem + 4160);
        const int t0 = bid * 8;
        const float* xg = x + (size_t)t0 * DDIM;
        #pragma unroll
        for (int p = 0; p < 4; ++p) {
            const int idx = p * 1024 + tid * 4;
            *(float4*)&xs[idx >> 9][idx & 511] = *(const float4*)(xg + idx);
        }
        __syncthreads();
        const int tl = tid >> 5, e = (tid >> 1) & 15, h = tid & 1;
        float a0 = 0.f, a1 = 0.f, a2 = 0.f, a3 = 0.f;
        #pragma unroll 8
        for (int it = 0; it < 64; ++it) {
            const int d = h * 256 + it * 4;
            const float4 xv = *(const float4*)&xs[tl][d];
            a0 = fmaf(xv.x, Wg[(d + 0) * 16 + e], a0);
            a1 = fmaf(xv.y, Wg[(d + 1) * 16 + e], a1);
            a2 = fmaf(xv.z, Wg[(d + 2) * 16 + e], a2);
            a3 = fmaf(xv.w, Wg[(d + 3) * 16 + e], a3);
        }
        lsm[tl][e][h] = (a0 + a1) + (a2 + a3);
        __syncthreads();
        if ((tid & 31) == 0) {
            float l[16];
            #pragma unroll
            for (int j = 0; j < NEXP; ++j) l[j] = lsm[tl][j][0] + lsm[tl][j][1] + bg[j];
            float m = -1e30f;
            #pragma unroll
            for (int j = 0; j < NEXP; ++j) m = fmaxf(m, l[j]);
            float s = 0.f;
            #pragma unroll
            for (int j = 0; j < NEXP; ++j) s += __expf(l[j] - m);
            int i0 = 0; float v0 = -1e30f;
            #pragma unroll
            for (int j = 0; j < NEXP; ++j)
                if (l[j] > v0) { v0 = l[j]; i0 = j; }
            int i1 = -1; float v1 = -1e30f;
            #pragma unroll
            for (int j = 0; j < NEXP; ++j)
                if (j != i0 && l[j] > v1) { v1 = l[j]; i1 = j; }
            const float w0 = __expf(v0 - m) / s;
            const float w1 = __expf(v1 - m) / s;
            const int t = t0 + tl;
            int p0 = atomicAdd(&counts[i0], 1);
            tok_list[i0 * NTOK + p0] = t;
            w_list[i0 * NTOK + p0] = w0;
            epos[t * 2 + 0] = (i0 << 16) | p0;
            int p1 = atomicAdd(&counts[i1], 1);
            tok_list[i1 * NTOK + p1] = t;
            w_list[i1 * NTOK + p1] = w1;
            epos[t * 2 + 1] = (i1 << 16) | p1;
        }
        return;
    }

    // ---------------- weight transpose+convert to fragment-tiled ----------
    bid -= 512;
    float (*tile)[65] = (float(*)[65])smem;   // [64][65]
    const float* src; ushort_t* dst; int R, C, NT, CK, rt, ct, e;
    if (bid < 4096) {      // W1: [512 k][2048 n], 8x32 64-tiles per expert
        e = bid >> 8; const int rem = bid & 255;
        rt = rem >> 5; ct = rem & 31;
        src = W1; dst = W1t; R = DDIM; C = HDIM; NT = 128; CK = 64;
    } else {               // W2: [2048 k][512 n], 32x8 64-tiles per expert
        bid -= 4096;
        e = bid >> 8; const int rem = bid & 255;
        rt = rem >> 3; ct = rem & 7;
        src = W2; dst = W2t; R = HDIM; C = DDIM; NT = 32; CK = 256;
    }
    const size_t zoff = (size_t)e * R * C;
    const int k0 = rt << 6, n0 = ct << 6;
    const int rr4 = (tid & 15) << 2;    // k within tile (x4)
    const int qq  = tid >> 4;
    #pragma unroll
    for (int p = 0; p < 4; ++p) {
        const int r = qq + (p << 4);
        const float4 v = *(const float4*)(src + zoff + (size_t)(k0 + r) * C + n0 + rr4);
        tile[r][rr4 + 0] = v.x; tile[r][rr4 + 1] = v.y;
        tile[r][rr4 + 2] = v.z; tile[r][rr4 + 3] = v.w;
    }
    __syncthreads();
    const int kk = k0 + rr4;
    #pragma unroll
    for (int p = 0; p < 4; ++p) {
        const int nl = qq + (p << 4);
        const int n = n0 + nl;
        ushort4 o = make_ushort4(f2bf(tile[rr4 + 0][nl]), f2bf(tile[rr4 + 1][nl]),
                                 f2bf(tile[rr4 + 2][nl]), f2bf(tile[rr4 + 3][nl]));
        const size_t off = (((size_t)e * NT + (n >> 4)) * CK + (kk >> 3)) * 128
                         + (size_t)(n & 15) * 8 + (kk & 7);
        *(ushort4*)(dst + off) = o;
    }
}

// offsets prefix-scan + 128-row tile list (sum ceil(Me/128) <= 79)
__global__ void scan_kernel(const int* __restrict__ counts, int* __restrict__ offsets,
                            int* __restrict__ tm, int* __restrict__ ntiles)
{
    if (threadIdx.x == 0 && blockIdx.x == 0) {
        int s = 0, nt = 0;
        for (int e = 0; e < NEXP; ++e) {
            offsets[e] = s;
            const int c = counts[e];
            s += c;
            const int t = (c + 127) >> 7;
            for (int i = 0; i < t; ++i) tm[nt++] = (e << 16) | i;
        }
        offsets[NEXP] = s;
        ntiles[0] = nt;
    }
}

// gather x rows (fp32) into fragment-tiled bf16 A, slot order per 128-tile
__global__ __launch_bounds__(256) void gather_xa(
    const float* __restrict__ x, const int* __restrict__ tok_list,
    const int* __restrict__ counts, const int* __restrict__ tm,
    const int* __restrict__ ntiles, ushort_t* __restrict__ xa)
{
    const int b = blockIdx.x;
    if (b >= ntiles[0]) return;
    const int info = tm[b];
    const int e = info >> 16, m0 = (info & 0xffff) << 7;
    const int Me = counts[e];
    const int row = threadIdx.x >> 1;
    const int half = threadIdx.x & 1;
    const int tok = tok_list[e * NTOK + min(m0 + row, Me - 1)];
    const float* src = x + (size_t)tok * DDIM + half * 256;
    ushort_t* dstb = xa + (size_t)b * 65536 + (size_t)(row >> 4) * 8192 + (row & 15) * 8;
    #pragma unroll 8
    for (int q = 0; q < 64; ++q) {
        const int k = half * 256 + q * 4;
        const float4 v = *(const float4*)(src + q * 4);
        ushort4 o = make_ushort4(f2bf(v.x), f2bf(v.y), f2bf(v.z), f2bf(v.w));
        *(ushort4*)(dstb + (size_t)(k >> 3) * 128 + (k & 7)) = o;
    }
}

// ---- GEMM1: barrier-free K-loop, frags direct from global (tiled layouts) --
// Block = 128m x 128n, 4 waves in 2x2, each 64x64 (acc 4x4 of 16x16x32).
__global__ __launch_bounds__(256) void gemm1_mfma(
    const ushort_t* __restrict__ xa, const ushort_t* __restrict__ W1t,
    const float* __restrict__ b1, const int* __restrict__ tm,
    const int* __restrict__ ntiles, ushort_t* __restrict__ hb)
{
    const int t = blockIdx.y;
    if (t >= ntiles[0]) return;
    const int e = tm[t] >> 16;
    const int n0 = blockIdx.x << 7;
    const int tid = threadIdx.x, lane = tid & 63, w = tid >> 6;
    const int fm = lane & 15, fq = lane >> 4;
    const int wr = (w >> 1) << 6, wc = (w & 1) << 6;

    const ushort_t* baseA = xa + (size_t)t * 65536
                          + (size_t)((w >> 1) * 4) * 8192 + lane * 8;
    const ushort_t* baseB = W1t + ((size_t)e * 128 + (n0 >> 4) + (w & 1) * 4) * 8192
                          + lane * 8;

    floatx4 acc[4][4] = {};
    #pragma unroll 4
    for (int kc = 0; kc < 16; ++kc) {
        short8 af[4], bf[4];
        #pragma unroll
        for (int i = 0; i < 4; ++i)
            af[i] = *(const short8*)(baseA + i * 8192 + kc * 512);
        #pragma unroll
        for (int j = 0; j < 4; ++j)
            bf[j] = *(const short8*)(baseB + j * 8192 + kc * 512);
        #pragma unroll
        for (int i = 0; i < 4; ++i)
            #pragma unroll
            for (int j = 0; j < 4; ++j)
                acc[i][j] = __builtin_amdgcn_mfma_f32_16x16x32_bf16(
                    af[i], bf[j], acc[i][j], 0, 0, 0);
    }

    // epilogue: relu(acc+bias) -> LDS -> coalesced tiled store to hb
    __shared__ ushort_t ls[128 * 128];
    #pragma unroll
    for (int j = 0; j < 4; ++j) {
        const float bias = b1[(size_t)e * HDIM + n0 + wc + j * 16 + fm];
        #pragma unroll
        for (int i = 0; i < 4; ++i)
            #pragma unroll
            for (int r = 0; r < 4; ++r) {
                const int row = wr + i * 16 + fq * 4 + r;
                ls[row * 128 + wc + j * 16 + fm] =
                    f2bf(fmaxf(acc[i][j][r] + bias, 0.f));
            }
    }
    __syncthreads();
    ushort_t* hbase = hb + (size_t)t * 262144 + (size_t)(n0 >> 3) * 128;
    #pragma unroll
    for (int p = 0; p < 8; ++p) {
        const int unit = tid + p * 256;
        const int row = unit >> 4, c16 = unit & 15;
        *(short8*)(hbase + (size_t)(row >> 4) * 32768 + (size_t)c16 * 128
                   + (row & 15) * 8) = *(const short8*)&ls[row * 128 + c16 * 8];
    }
    // pad rows (m>=Me) hold duplicated data; gemm2 epilogue masks them.
}

// ---- GEMM2: same structure, K=2048 split-K=2, bf16 partials to ybuf -------
__global__ __launch_bounds__(256) void gemm2_mfma(
    const ushort_t* __restrict__ hb, const ushort_t* __restrict__ W2t,
    const float* __restrict__ b2, const float* __restrict__ w_list,
    const int* __restrict__ counts, const int* __restrict__ offsets,
    const int* __restrict__ tm, const int* __restrict__ ntiles,
    ushort_t* __restrict__ yb)
{
    const int t = blockIdx.y;
    if (t >= ntiles[0]) return;
    const int info = tm[t];
    const int e = info >> 16, m0 = (info & 0xffff) << 7;
    const int Me = counts[e], aoff = offsets[e];
    const int n0 = blockIdx.x << 7;
    const int kz = blockIdx.z;
    const int tid = threadIdx.x, lane = tid & 63, w = tid >> 6;
    const int fm = lane & 15, fq = lane >> 4;
    const int wr = (w >> 1) << 6, wc = (w & 1) << 6;

    const ushort_t* baseA = hb + (size_t)t * 262144
                          + (size_t)((w >> 1) * 4) * 32768 + kz * 16384 + lane * 8;
    const ushort_t* baseB = W2t + ((size_t)e * 32 + (n0 >> 4) + (w & 1) * 4) * 32768
                          + kz * 16384 + lane * 8;

    floatx4 acc[4][4] = {};
    #pragma unroll 4
    for (int kc = 0; kc < 32; ++kc) {
        short8 af[4], bf[4];
        #pragma unroll
        for (int i = 0; i < 4; ++i)
            af[i] = *(const short8*)(baseA + i * 32768 + kc * 512);
        #pragma unroll
        for (int j = 0; j < 4; ++j)
            bf[j] = *(const short8*)(baseB + j * 32768 + kc * 512);
        #pragma unroll
        for (int i = 0; i < 4; ++i)
            #pragma unroll
            for (int j = 0; j < 4; ++j)
                acc[i][j] = __builtin_amdgcn_mfma_f32_16x16x32_bf16(
                    af[i], bf[j], acc[i][j], 0, 0, 0);
    }

    __shared__ ushort_t ls[128 * 128];
    #pragma unroll
    for (int j = 0; j < 4; ++j) {
        const float bias = (kz == 0) ? b2[(size_t)e * DDIM + n0 + wc + j * 16 + fm] : 0.f;
        #pragma unroll
        for (int i = 0; i < 4; ++i)
            #pragma unroll
            for (int r = 0; r < 4; ++r) {
                const int row = wr + i * 16 + fq * 4 + r;
                const float gw = w_list[e * NTOK + min(m0 + row, Me - 1)];
                ls[row * 128 + wc + j * 16 + fm] = f2bf(gw * (acc[i][j][r] + bias));
            }
    }
    __syncthreads();
    ushort_t* ybase = yb + (size_t)kz * (8192 * 512) + n0;
    #pragma unroll
    for (int p = 0; p < 8; ++p) {
        const int unit = tid + p * 256;
        const int row = unit >> 4, c16 = unit & 15;
        if (m0 + row < Me)
            *(short8*)(ybase + (size_t)(aoff + m0 + row) * 512 + c16 * 8)
                = *(const short8*)&ls[row * 128 + c16 * 8];
    }
}

// out = LayerNorm(x + y[0][r0] + y[1][r0] + y[0][r1] + y[1][r1]) * gamma + beta
__global__ __launch_bounds__(256) void ln_kernel(
    const float* __restrict__ x, const ushort_t* __restrict__ yb,
    const int* __restrict__ epos, const int* __restrict__ offsets,
    const float* __restrict__ gamma, const float* __restrict__ beta,
    float* __restrict__ out)
{
    const int t = blockIdx.x * 4 + (threadIdx.x >> 6);
    const int lane = threadIdx.x & 63;
    const int d0 = lane * 8;

    const int p0 = epos[2 * t + 0];
    const int p1 = epos[2 * t + 1];
    const size_t r0 = (size_t)(offsets[p0 >> 16] + (p0 & 0xFFFF));
    const size_t r1 = (size_t)(offsets[p1 >> 16] + (p1 & 0xFFFF));

    const short8 y0 = *(const short8*)(yb + r0 * 512 + d0);
    const short8 y1 = *(const short8*)(yb + (size_t)8192 * 512 + r0 * 512 + d0);
    const short8 y2 = *(const short8*)(yb + r1 * 512 + d0);
    const short8 y3 = *(const short8*)(yb + (size_t)8192 * 512 + r1 * 512 + d0);
    float xv[8];
    *(float4*)&xv[0] = *(const float4*)(x + (size_t)t * DDIM + d0);
    *(float4*)&xv[4] = *(const float4*)(x + (size_t)t * DDIM + d0 + 4);

    float v[8];
    float s = 0.f;
    #pragma unroll
    for (int i = 0; i < 8; ++i) {
        v[i] = xv[i] + bf2f((ushort_t)y0[i]) + bf2f((ushort_t)y1[i])
                     + bf2f((ushort_t)y2[i]) + bf2f((ushort_t)y3[i]);
        s += v[i];
    }
    #pragma unroll
    for (int o = 32; o > 0; o >>= 1) s += __shfl_xor(s, o, 64);
    const float mu = s * (1.f / DDIM);
    float q = 0.f;
    #pragma unroll
    for (int i = 0; i < 8; ++i) { const float d_ = v[i] - mu; q = fmaf(d_, d_, q); }
    #pragma unroll
    for (int o = 32; o > 0; o >>= 1) q += __shfl_xor(q, o, 64);
    const float rstd = rsqrtf(q * (1.f / DDIM) + 1e-5f);

    float g[8], bt[8], o8[8];
    *(float4*)&g[0] = *(const float4*)(gamma + d0);
    *(float4*)&g[4] = *(const float4*)(gamma + d0 + 4);
    *(float4*)&bt[0] = *(const float4*)(beta + d0);
    *(float4*)&bt[4] = *(const float4*)(beta + d0 + 4);
    #pragma unroll
    for (int i = 0; i < 8; ++i) o8[i] = (v[i] - mu) * rstd * g[i] + bt[i];
    *(float4*)(out + (size_t)t * DDIM + d0) = *(float4*)&o8[0];
    *(float4*)(out + (size_t)t * DDIM + d0 + 4) = *(float4*)&o8[4];
}

extern "C" void kernel_launch(void* const* d_in, const int* in_sizes, int n_in,
                              void* d_out, int out_size, void* d_ws, size_t ws_size,
                              hipStream_t stream) {
    const float* x     = (const float*)d_in[0];
    const float* Wg    = (const float*)d_in[1];
    const float* bg    = (const float*)d_in[2];
    const float* W1    = (const float*)d_in[3];
    const float* b1    = (const float*)d_in[4];
    const float* W2    = (const float*)d_in[5];
    const float* b2    = (const float*)d_in[6];
    const float* gamma = (const float*)d_in[7];
    const float* beta  = (const float*)d_in[8];
    float* out = (float*)d_out;

    char* ws = (char*)d_ws;
    int*      counts   = (int*)(ws + WS_COUNTS);
    int*      offsets  = (int*)(ws + WS_OFFSETS);
    int*      ntiles   = (int*)(ws + WS_NTILES);
    int*      tm       = (int*)(ws + WS_TM);
    int*      epos     = (int*)(ws + WS_EPOS);
    int*      tok_list = (int*)(ws + WS_TOK);
    float*    w_list   = (float*)(ws + WS_WL);
    ushort_t* xa       = (ushort_t*)(ws + WS_XA);
    ushort_t* W1t      = (ushort_t*)(ws + WS_W1T);
    ushort_t* W2t      = (ushort_t*)(ws + WS_W2T);
    ushort_t* hb       = (ushort_t*)(ws + WS_HB);
    ushort_t* yb       = (ushort_t*)(ws + WS_YB);   // aliases W1t (dead by then)

    hipMemsetAsync(counts, 0, 64, stream);
    prep_kernel<<<8704, 256, 0, stream>>>(x, Wg, bg, W1, W2, counts,
                                          tok_list, w_list, epos, W1t, W2t);
    scan_kernel<<<1, 64, 0, stream>>>(counts, offsets, tm, ntiles);
    gather_xa<<<80, 256, 0, stream>>>(x, tok_list, counts, tm, ntiles, xa);
    gemm1_mfma<<<dim3(HDIM / 128, 80), 256, 0, stream>>>(
        xa, W1t, b1, tm, ntiles, hb);
    gemm2_mfma<<<dim3(DDIM / 128, 80, 2), 256, 0, stream>>>(
        hb, W2t, b2, w_list, counts, offsets, tm, ntiles, yb);
    ln_kernel<<<NTOK / 4, 256, 0, stream>>>(x, yb, epos, offsets, gamma, beta, out);
}

// Round 5
// 325.558 us; speedup vs baseline: 1.3487x; 1.0381x over previous
//
#include <hip/hip_runtime.h>
#include <math.h>

// Problem constants (B=2, S=2048 -> N=4096 tokens)
#define NTOK 4096
#define DDIM 512
#define HDIM 2048
#define NEXP 16

// Fragment-tiled layouts: elem(e_or_t, row, k) =
//   ((tile16 * CK + (k>>3)) * 128) + (row&15)*8 + (k&7)
// so a 64-lane b128 load (lane*16B) fetches rows r0..r0+15 x k-chunk32 — one
// MFMA fragment set, fully coalesced. No LDS needed in the GEMM K-loop.

// Workspace layout (bytes). Total ~115 MB (<= known-good 125.8 MB).
#define WS_COUNTS    0u
#define WS_OFFSETS   256u
#define WS_NTILES    512u
#define WS_TM        768u          // <=80 ints
#define WS_EPOS      4096u         // NTOK*2 ints (32 KB)
#define WS_TOK       36864u        // NEXP*NTOK ints (256 KB)
#define WS_WL        299008u       // NEXP*NTOK floats (256 KB)
#define WS_XA        1048576u      // tiled A for gemm1: 80*128*512 bf16 = 10.5 MB
#define WS_W1T       11534336u     // tiled [e][nt128][c64][16][8] bf16 = 33.5 MB
#define WS_W2T       45088768u     // tiled [e][nt32][c256][16][8] bf16 = 33.5 MB
#define WS_HB        78643200u     // tiled [t80][sub8][c256][16][8] bf16 = 41.9 MB
#define WS_YB        WS_W1T        // ybuf [2][8192][512] bf16 = 16.8 MB, aliases W1T
                                   // (W1T dead after gemm1; stream is serial)

typedef __attribute__((ext_vector_type(8))) short short8;
typedef __attribute__((ext_vector_type(4))) float floatx4;
typedef unsigned short ushort_t;

__device__ __forceinline__ ushort_t f2bf(float f) {
    unsigned u = __float_as_uint(f);
    u += 0x7fffu + ((u >> 16) & 1u);   // round-to-nearest-even
    return (ushort_t)(u >> 16);
}
__device__ __forceinline__ float bf2f(ushort_t u) {
    return __uint_as_float((unsigned)u << 16);
}

// ---- prep: blocks 0..511 = gating (8 tokens each); 512..8703 = W transpose --
__global__ __launch_bounds__(256) void prep_kernel(
    const float* __restrict__ x, const float* __restrict__ Wg,
    const float* __restrict__ bg, const float* __restrict__ W1,
    const float* __restrict__ W2, int* __restrict__ counts,
    int* __restrict__ tok_list, float* __restrict__ w_list,
    int* __restrict__ epos, ushort_t* __restrict__ W1t,
    ushort_t* __restrict__ W2t)
{
    __shared__ float smem[4416];
    const int tid = threadIdx.x;
    int bid = blockIdx.x;

    if (bid < 512) {
        // ---------------- gating ----------------
        float (*xs)[520] = (float(*)[520])smem;              // 8x520
        float (*lsm)[16][2] = (float(*)[16][2])(smem + 4160);
        const int t0 = bid * 8;
        const float* xg = x + (size_t)t0 * DDIM;
        #pragma unroll
        for (int p = 0; p < 4; ++p) {
            const int idx = p * 1024 + tid * 4;
            *(float4*)&xs[idx >> 9][idx & 511] = *(const float4*)(xg + idx);
        }
        __syncthreads();
        const int tl = tid >> 5, e = (tid >> 1) & 15, h = tid & 1;
        float a0 = 0.f, a1 = 0.f, a2 = 0.f, a3 = 0.f;
        #pragma unroll 8
        for (int it = 0; it < 64; ++it) {
            const int d = h * 256 + it * 4;
            const float4 xv = *(const float4*)&xs[tl][d];
            a0 = fmaf(xv.x, Wg[(d + 0) * 16 + e], a0);
            a1 = fmaf(xv.y, Wg[(d + 1) * 16 + e], a1);
            a2 = fmaf(xv.z, Wg[(d + 2) * 16 + e], a2);
            a3 = fmaf(xv.w, Wg[(d + 3) * 16 + e], a3);
        }
        lsm[tl][e][h] = (a0 + a1) + (a2 + a3);
        __syncthreads();
        if ((tid & 31) == 0) {
            float l[16];
            #pragma unroll
            for (int j = 0; j < NEXP; ++j) l[j] = lsm[tl][j][0] + lsm[tl][j][1] + bg[j];
            float m = -1e30f;
            #pragma unroll
            for (int j = 0; j < NEXP; ++j) m = fmaxf(m, l[j]);
            float s = 0.f;
            #pragma unroll
            for (int j = 0; j < NEXP; ++j) s += __expf(l[j] - m);
            int i0 = 0; float v0 = -1e30f;
            #pragma unroll
            for (int j = 0; j < NEXP; ++j)
                if (l[j] > v0) { v0 = l[j]; i0 = j; }
            int i1 = -1; float v1 = -1e30f;
            #pragma unroll
            for (int j = 0; j < NEXP; ++j)
                if (j != i0 && l[j] > v1) { v1 = l[j]; i1 = j; }
            const float w0 = __expf(v0 - m) / s;
            const float w1 = __expf(v1 - m) / s;
            const int t = t0 + tl;
            int p0 = atomicAdd(&counts[i0], 1);
            tok_list[i0 * NTOK + p0] = t;
            w_list[i0 * NTOK + p0] = w0;
            epos[t * 2 + 0] = (i0 << 16) | p0;
            int p1 = atomicAdd(&counts[i1], 1);
            tok_list[i1 * NTOK + p1] = t;
            w_list[i1 * NTOK + p1] = w1;
            epos[t * 2 + 1] = (i1 << 16) | p1;
        }
        return;
    }

    // ------- weight transpose+convert to fragment-tiled, coalesced stores ----
    // A 64x64 (k x n) region maps to 4 contiguous 2 KB output runs (one per
    // 16-n subtile). Wave w owns subtile w; lane l pass p emits one short8 at
    // run_base + (l+64p)*8 elems -> 1 KB contiguous per wave-store. [R4 post-
    // mortem: scattered 8 B stores were the 3x gap vs BW floor.]
    bid -= 512;
    float (*tile)[65] = (float(*)[65])smem;   // [64][65]
    const float* src; ushort_t* dst; int R, C, NT, CK, rt, ct, e;
    if (bid < 4096) {      // W1: [512 k][2048 n], 8x32 64-tiles per expert
        e = bid >> 8; const int rem = bid & 255;
        rt = rem >> 5; ct = rem & 31;
        src = W1; dst = W1t; R = DDIM; C = HDIM; NT = 128; CK = 64;
    } else {               // W2: [2048 k][512 n], 32x8 64-tiles per expert
        bid -= 4096;
        e = bid >> 8; const int rem = bid & 255;
        rt = rem >> 3; ct = rem & 7;
        src = W2; dst = W2t; R = HDIM; C = DDIM; NT = 32; CK = 256;
    }
    const size_t zoff = (size_t)e * R * C;
    const int k0 = rt << 6, n0 = ct << 6;
    {
        const int cc4 = (tid & 15) << 2;
        const int qq  = tid >> 4;
        #pragma unroll
        for (int p = 0; p < 4; ++p) {
            const int r = qq + (p << 4);
            const float4 v = *(const float4*)(src + zoff + (size_t)(k0 + r) * C + n0 + cc4);
            tile[r][cc4 + 0] = v.x; tile[r][cc4 + 1] = v.y;
            tile[r][cc4 + 2] = v.z; tile[r][cc4 + 3] = v.w;
        }
    }
    __syncthreads();
    const int w = tid >> 6;          // subtile (nsub)
    const int l = tid & 63;
    ushort_t* run = dst + (((size_t)e * NT + (n0 >> 4) + w) * CK + (k0 >> 3)) * 128;
    #pragma unroll
    for (int p = 0; p < 2; ++p) {
        const int lidx = l + (p << 6);        // 0..127
        const int kc = lidx >> 4;             // k-chunk within tile
        const int nl = lidx & 15;             // n within subtile
        const int col = (w << 4) + nl;
        short8 o;
        #pragma unroll
        for (int j = 0; j < 8; ++j)
            o[j] = (short)f2bf(tile[(kc << 3) + j][col]);
        *(short8*)(run + (size_t)lidx * 8) = o;
    }
}

// offsets prefix-scan + 128-row tile list (sum ceil(Me/128) <= 79)
__global__ void scan_kernel(const int* __restrict__ counts, int* __restrict__ offsets,
                            int* __restrict__ tm, int* __restrict__ ntiles)
{
    if (threadIdx.x == 0 && blockIdx.x == 0) {
        int s = 0, nt = 0;
        for (int e = 0; e < NEXP; ++e) {
            offsets[e] = s;
            const int c = counts[e];
            s += c;
            const int t = (c + 127) >> 7;
            for (int i = 0; i < t; ++i) tm[nt++] = (e << 16) | i;
        }
        offsets[NEXP] = s;
        ntiles[0] = nt;
    }
}

// gather x rows (fp32) into fragment-tiled bf16 A, slot order per 128-tile.
// Grid (80 tiles, 4 k-slices): 4x the blocks of R4 -> shorter latency chains.
__global__ __launch_bounds__(256) void gather_xa(
    const float* __restrict__ x, const int* __restrict__ tok_list,
    const int* __restrict__ counts, const int* __restrict__ tm,
    const int* __restrict__ ntiles, ushort_t* __restrict__ xa)
{
    const int b = blockIdx.x;
    if (b >= ntiles[0]) return;
    const int info = tm[b];
    const int e = info >> 16, m0 = (info & 0xffff) << 7;
    const int Me = counts[e];
    const int row = threadIdx.x >> 1;
    const int half = threadIdx.x & 1;
    const int kbase = blockIdx.y * 128 + half * 64;
    const int tok = tok_list[e * NTOK + min(m0 + row, Me - 1)];
    const float* src = x + (size_t)tok * DDIM + kbase;
    ushort_t* dstb = xa + (size_t)b * 65536 + (size_t)(row >> 4) * 8192 + (row & 15) * 8;
    #pragma unroll
    for (int q = 0; q < 16; ++q) {
        const int k = kbase + q * 4;
        const float4 v = *(const float4*)(src + q * 4);
        ushort4 o = make_ushort4(f2bf(v.x), f2bf(v.y), f2bf(v.z), f2bf(v.w));
        *(ushort4*)(dstb + (size_t)(k >> 3) * 128 + (k & 7)) = o;
    }
}

// ---- GEMM1: barrier-free K-loop, frags direct from global (tiled layouts) --
// Block = 128m x 128n, 4 waves in 2x2, each 64x64 (acc 4x4 of 16x16x32).
__global__ __launch_bounds__(256) void gemm1_mfma(
    const ushort_t* __restrict__ xa, const ushort_t* __restrict__ W1t,
    const float* __restrict__ b1, const int* __restrict__ tm,
    const int* __restrict__ ntiles, ushort_t* __restrict__ hb)
{
    const int t = blockIdx.y;
    if (t >= ntiles[0]) return;
    const int e = tm[t] >> 16;
    const int n0 = blockIdx.x << 7;
    const int tid = threadIdx.x, lane = tid & 63, w = tid >> 6;
    const int fm = lane & 15, fq = lane >> 4;
    const int wr = (w >> 1) << 6, wc = (w & 1) << 6;

    const ushort_t* baseA = xa + (size_t)t * 65536
                          + (size_t)((w >> 1) * 4) * 8192 + lane * 8;
    const ushort_t* baseB = W1t + ((size_t)e * 128 + (n0 >> 4) + (w & 1) * 4) * 8192
                          + lane * 8;

    floatx4 acc[4][4] = {};
    #pragma unroll 4
    for (int kc = 0; kc < 16; ++kc) {
        short8 af[4], bf[4];
        #pragma unroll
        for (int i = 0; i < 4; ++i)
            af[i] = *(const short8*)(baseA + i * 8192 + kc * 512);
        #pragma unroll
        for (int j = 0; j < 4; ++j)
            bf[j] = *(const short8*)(baseB + j * 8192 + kc * 512);
        #pragma unroll
        for (int i = 0; i < 4; ++i)
            #pragma unroll
            for (int j = 0; j < 4; ++j)
                acc[i][j] = __builtin_amdgcn_mfma_f32_16x16x32_bf16(
                    af[i], bf[j], acc[i][j], 0, 0, 0);
    }

    // epilogue: relu(acc+bias) -> LDS -> coalesced tiled store to hb
    __shared__ ushort_t ls[128 * 128];
    #pragma unroll
    for (int j = 0; j < 4; ++j) {
        const float bias = b1[(size_t)e * HDIM + n0 + wc + j * 16 + fm];
        #pragma unroll
        for (int i = 0; i < 4; ++i)
            #pragma unroll
            for (int r = 0; r < 4; ++r) {
                const int row = wr + i * 16 + fq * 4 + r;
                ls[row * 128 + wc + j * 16 + fm] =
                    f2bf(fmaxf(acc[i][j][r] + bias, 0.f));
            }
    }
    __syncthreads();
    ushort_t* hbase = hb + (size_t)t * 262144 + (size_t)(n0 >> 3) * 128;
    #pragma unroll
    for (int p = 0; p < 8; ++p) {
        const int unit = tid + p * 256;
        const int row = unit >> 4, c16 = unit & 15;
        *(short8*)(hbase + (size_t)(row >> 4) * 32768 + (size_t)c16 * 128
                   + (row & 15) * 8) = *(const short8*)&ls[row * 128 + c16 * 8];
    }
    // pad rows (m>=Me) hold duplicated data; gemm2 epilogue masks them.
}

// ---- GEMM2: same structure, K=2048 split-K=2, bf16 partials to ybuf -------
__global__ __launch_bounds__(256) void gemm2_mfma(
    const ushort_t* __restrict__ hb, const ushort_t* __restrict__ W2t,
    const float* __restrict__ b2, const float* __restrict__ w_list,
    const int* __restrict__ counts, const int* __restrict__ offsets,
    const int* __restrict__ tm, const int* __restrict__ ntiles,
    ushort_t* __restrict__ yb)
{
    const int t = blockIdx.y;
    if (t >= ntiles[0]) return;
    const int info = tm[t];
    const int e = info >> 16, m0 = (info & 0xffff) << 7;
    const int Me = counts[e], aoff = offsets[e];
    const int n0 = blockIdx.x << 7;
    const int kz = blockIdx.z;
    const int tid = threadIdx.x, lane = tid & 63, w = tid >> 6;
    const int fm = lane & 15, fq = lane >> 4;
    const int wr = (w >> 1) << 6, wc = (w & 1) << 6;

    const ushort_t* baseA = hb + (size_t)t * 262144
                          + (size_t)((w >> 1) * 4) * 32768 + kz * 16384 + lane * 8;
    const ushort_t* baseB = W2t + ((size_t)e * 32 + (n0 >> 4) + (w & 1) * 4) * 32768
                          + kz * 16384 + lane * 8;

    floatx4 acc[4][4] = {};
    #pragma unroll 4
    for (int kc = 0; kc < 32; ++kc) {
        short8 af[4], bf[4];
        #pragma unroll
        for (int i = 0; i < 4; ++i)
            af[i] = *(const short8*)(baseA + i * 32768 + kc * 512);
        #pragma unroll
        for (int j = 0; j < 4; ++j)
            bf[j] = *(const short8*)(baseB + j * 32768 + kc * 512);
        #pragma unroll
        for (int i = 0; i < 4; ++i)
            #pragma unroll
            for (int j = 0; j < 4; ++j)
                acc[i][j] = __builtin_amdgcn_mfma_f32_16x16x32_bf16(
                    af[i], bf[j], acc[i][j], 0, 0, 0);
    }

    __shared__ ushort_t ls[128 * 128];
    #pragma unroll
    for (int j = 0; j < 4; ++j) {
        const float bias = (kz == 0) ? b2[(size_t)e * DDIM + n0 + wc + j * 16 + fm] : 0.f;
        #pragma unroll
        for (int i = 0; i < 4; ++i)
            #pragma unroll
            for (int r = 0; r < 4; ++r) {
                const int row = wr + i * 16 + fq * 4 + r;
                const float gw = w_list[e * NTOK + min(m0 + row, Me - 1)];
                ls[row * 128 + wc + j * 16 + fm] = f2bf(gw * (acc[i][j][r] + bias));
            }
    }
    __syncthreads();
    ushort_t* ybase = yb + (size_t)kz * (8192 * 512) + n0;
    #pragma unroll
    for (int p = 0; p < 8; ++p) {
        const int unit = tid + p * 256;
        const int row = unit >> 4, c16 = unit & 15;
        if (m0 + row < Me)
            *(short8*)(ybase + (size_t)(aoff + m0 + row) * 512 + c16 * 8)
                = *(const short8*)&ls[row * 128 + c16 * 8];
    }
}

// out = LayerNorm(x + y[0][r0] + y[1][r0] + y[0][r1] + y[1][r1]) * gamma + beta
__global__ __launch_bounds__(256) void ln_kernel(
    const float* __restrict__ x, const ushort_t* __restrict__ yb,
    const int* __restrict__ epos, const int* __restrict__ offsets,
    const float* __restrict__ gamma, const float* __restrict__ beta,
    float* __restrict__ out)
{
    const int t = blockIdx.x * 4 + (threadIdx.x >> 6);
    const int lane = threadIdx.x & 63;
    const int d0 = lane * 8;

    const int p0 = epos[2 * t + 0];
    const int p1 = epos[2 * t + 1];
    const size_t r0 = (size_t)(offsets[p0 >> 16] + (p0 & 0xFFFF));
    const size_t r1 = (size_t)(offsets[p1 >> 16] + (p1 & 0xFFFF));

    const short8 y0 = *(const short8*)(yb + r0 * 512 + d0);
    const short8 y1 = *(const short8*)(yb + (size_t)8192 * 512 + r0 * 512 + d0);
    const short8 y2 = *(const short8*)(yb + r1 * 512 + d0);
    const short8 y3 = *(const short8*)(yb + (size_t)8192 * 512 + r1 * 512 + d0);
    float xv[8];
    *(float4*)&xv[0] = *(const float4*)(x + (size_t)t * DDIM + d0);
    *(float4*)&xv[4] = *(const float4*)(x + (size_t)t * DDIM + d0 + 4);

    float v[8];
    float s = 0.f;
    #pragma unroll
    for (int i = 0; i < 8; ++i) {
        v[i] = xv[i] + bf2f((ushort_t)y0[i]) + bf2f((ushort_t)y1[i])
                     + bf2f((ushort_t)y2[i]) + bf2f((ushort_t)y3[i]);
        s += v[i];
    }
    #pragma unroll
    for (int o = 32; o > 0; o >>= 1) s += __shfl_xor(s, o, 64);
    const float mu = s * (1.f / DDIM);
    float q = 0.f;
    #pragma unroll
    for (int i = 0; i < 8; ++i) { const float d_ = v[i] - mu; q = fmaf(d_, d_, q); }
    #pragma unroll
    for (int o = 32; o > 0; o >>= 1) q += __shfl_xor(q, o, 64);
    const float rstd = rsqrtf(q * (1.f / DDIM) + 1e-5f);

    float g[8], bt[8], o8[8];
    *(float4*)&g[0] = *(const float4*)(gamma + d0);
    *(float4*)&g[4] = *(const float4*)(gamma + d0 + 4);
    *(float4*)&bt[0] = *(const float4*)(beta + d0);
    *(float4*)&bt[4] = *(const float4*)(beta + d0 + 4);
    #pragma unroll
    for (int i = 0; i < 8; ++i) o8[i] = (v[i] - mu) * rstd * g[i] + bt[i];
    *(float4*)(out + (size_t)t * DDIM + d0) = *(float4*)&o8[0];
    *(float4*)(out + (size_t)t * DDIM + d0 + 4) = *(float4*)&o8[4];
}

extern "C" void kernel_launch(void* const* d_in, const int* in_sizes, int n_in,
                              void* d_out, int out_size, void* d_ws, size_t ws_size,
                              hipStream_t stream) {
    const float* x     = (const float*)d_in[0];
    const float* Wg    = (const float*)d_in[1];
    const float* bg    = (const float*)d_in[2];
    const float* W1    = (const float*)d_in[3];
    const float* b1    = (const float*)d_in[4];
    const float* W2    = (const float*)d_in[5];
    const float* b2    = (const float*)d_in[6];
    const float* gamma = (const float*)d_in[7];
    const float* beta  = (const float*)d_in[8];
    float* out = (float*)d_out;

    char* ws = (char*)d_ws;
    int*      counts   = (int*)(ws + WS_COUNTS);
    int*      offsets  = (int*)(ws + WS_OFFSETS);
    int*      ntiles   = (int*)(ws + WS_NTILES);
    int*      tm       = (int*)(ws + WS_TM);
    int*      epos     = (int*)(ws + WS_EPOS);
    int*      tok_list = (int*)(ws + WS_TOK);
    float*    w_list   = (float*)(ws + WS_WL);
    ushort_t* xa       = (ushort_t*)(ws + WS_XA);
    ushort_t* W1t      = (ushort_t*)(ws + WS_W1T);
    ushort_t* W2t      = (ushort_t*)(ws + WS_W2T);
    ushort_t* hb       = (ushort_t*)(ws + WS_HB);
    ushort_t* yb       = (ushort_t*)(ws + WS_YB);   // aliases W1t (dead by then)

    hipMemsetAsync(counts, 0, 64, stream);
    prep_kernel<<<8704, 256, 0, stream>>>(x, Wg, bg, W1, W2, counts,
                                          tok_list, w_list, epos, W1t, W2t);
    scan_kernel<<<1, 64, 0, stream>>>(counts, offsets, tm, ntiles);
    gather_xa<<<dim3(80, 4), 256, 0, stream>>>(x, tok_list, counts, tm, ntiles, xa);
    gemm1_mfma<<<dim3(HDIM / 128, 80), 256, 0, stream>>>(
        xa, W1t, b1, tm, ntiles, hb);
    gemm2_mfma<<<dim3(DDIM / 128, 80, 2), 256, 0, stream>>>(
        hb, W2t, b2, w_list, counts, offsets, tm, ntiles, yb);
    ln_kernel<<<NTOK / 4, 256, 0, stream>>>(x, yb, epos, offsets, gamma, beta, out);
}